// Round 15
// baseline (349.004 us; speedup 1.0000x reference)
//
#include <hip/hip_runtime.h>
#include <hip/hip_bf16.h>

#define NUM_RAYS 4096
#define S_PER 96
#define NPTS (NUM_RAYS * S_PER)
#define CCH 80
#define HID 64

// ws layout (byte offsets)
#define WSB_W2     256       // 256 f32 (64x4)
#define WSB_B1     1536      // 64 f32
#define WSB_B2     1856      // 4 f32
#define WSB_W1S    4096      // 15360 bf16 shorts, compact MFMA B-frag order (30720 B)
#define WSB_PT     40960     // 983040 bf16: planesT [p][y*64+x][80]  (1.97 MB)

// w1s compact layout (shorts): plane p base = p*5120;
//  ccl 0,1: + ccl*2048 + (nb*64+lane)*8 + j        (k = 8*quad+j, ch = ccl*32+k)
//  ccl 2:   + 4096     + (nb*32+(lane&31))*8 + j   (quads 0,1 only; ch = 64+8*quad+j)

// d_out layout (elements of output dtype):
// [0) comp_rgb 3*4096 | [12288) depth 4096 | [16384) opacity 4096
// [20480) comp_normal 3*4096 | [32768) sdf_grad 393216*3

typedef __attribute__((ext_vector_type(8))) short short8;
typedef __attribute__((ext_vector_type(4))) float f32x4;

__device__ __forceinline__ float bf2f(__hip_bfloat16 v) { return __bfloat162float(v); }

__device__ __forceinline__ short f2bs(float f) {
  __hip_bfloat16 h = __float2bfloat16(f);
  short s; __builtin_memcpy(&s, &h, 2); return s;
}

template <bool BF16>
__device__ __forceinline__ float ldin(const void* p, size_t i) {
  if (BF16) return bf2f(((const __hip_bfloat16*)p)[i]);
  else      return ((const float*)p)[i];
}
template <bool BF16>
__device__ __forceinline__ void stout(void* p, size_t i, float v) {
  if (BF16) ((__hip_bfloat16*)p)[i] = __float2bfloat16(v);
  else      ((float*)p)[i] = v;
}

// Per-wave dtype self-detection: bf16 ray-dir norms ~1; f32-misread is garbage.
__device__ __forceinline__ bool detect_bf16(const void* rdv) {
  int lane = threadIdx.x & 63;
  const __hip_bfloat16* p = (const __hip_bfloat16*)rdv;
  float x = bf2f(p[lane * 3 + 0]);
  float y = bf2f(p[lane * 3 + 1]);
  float z = bf2f(p[lane * 3 + 2]);
  float n2 = x * x + y * y + z * z;
  bool ok = (n2 > 0.95f) && (n2 < 1.05f);
  return __ballot(ok) == ~0ull;
}

template <bool BF16>
__device__ __forceinline__ void prep_body(const void* __restrict__ W1,
                                          const void* __restrict__ b1,
                                          const void* __restrict__ W2,
                                          const void* __restrict__ b2,
                                          float* __restrict__ ws, int tid) {
  unsigned short* w1sw = (unsigned short*)((char*)ws + WSB_W1S);
  if (tid < 15360) {
    int p = tid / 5120;
    int r = tid - p * 5120;
    int ch, n;
    if (r < 4096) {
      int ccl  = r >> 11;
      int r2   = r & 2047;
      int j    = r2 & 7;
      int lane = (r2 >> 3) & 63;
      int nb   = r2 >> 9;
      ch = ccl * 32 + 8 * (lane >> 4) + j;
      n  = nb * 16 + (lane & 15);
    } else {
      int r2   = r - 4096;
      int j    = r2 & 7;
      int l31  = (r2 >> 3) & 31;
      int nb   = r2 >> 8;
      ch = 64 + 8 * (l31 >> 4) + j;
      n  = nb * 16 + (l31 & 15);
    }
    w1sw[tid] = (unsigned short)f2bs(ldin<BF16>(W1, (size_t)(p * 80 + ch) * 64 + n));
  }
  float* w2f = (float*)((char*)ws + WSB_W2);
  float* b1f = (float*)((char*)ws + WSB_B1);
  float* b2f = (float*)((char*)ws + WSB_B2);
  if (tid < 256) w2f[tid] = ldin<BF16>(W2, tid);
  if (tid < 64)  b1f[tid] = ldin<BF16>(b1, tid);
  if (tid < 4)   b2f[tid] = ldin<BF16>(b2, tid);
}

// planes[p][c][y][x] -> planesT[p][y*64+x][80] (bf16, channel-last).
template <bool BF16>
__device__ __forceinline__ void transpose_body(const void* __restrict__ planes,
                                               float* __restrict__ ws) {
  int b  = blockIdx.x;
  int tt = b & 15;
  int ct = (b >> 4) % 5;
  int p  = b / 80;
  int tex = tt * 256 + threadIdx.x;
  unsigned u[8];
  #pragma unroll
  for (int i = 0; i < 8; i++) {
    int c0 = ct * 16 + 2 * i;
    float v0 = ldin<BF16>(planes, ((size_t)(p * 80 + c0) * 4096) + tex);
    float v1 = ldin<BF16>(planes, ((size_t)(p * 80 + c0 + 1) * 4096) + tex);
    unsigned s0 = (unsigned short)f2bs(v0);
    unsigned s1 = (unsigned short)f2bs(v1);
    u[i] = s0 | (s1 << 16);
  }
  unsigned short* ptb = (unsigned short*)((char*)ws + WSB_PT);
  uint4* dst = (uint4*)(ptb + ((size_t)(p * 4096 + tex) * 80 + ct * 16));
  dst[0] = make_uint4(u[0], u[1], u[2], u[3]);
  dst[1] = make_uint4(u[4], u[5], u[6], u[7]);
}

// blocks 0..239: plane transpose; blocks 240..303: weight prep
__global__ void setup_kernel(const void* __restrict__ planes,
                             const void* __restrict__ W1,
                             const void* __restrict__ b1,
                             const void* __restrict__ W2,
                             const void* __restrict__ b2,
                             const void* __restrict__ rd,
                             float* __restrict__ ws) {
  bool bf = detect_bf16(rd);
  if (blockIdx.x < 240) {
    if (bf) transpose_body<true >(planes, ws);
    else    transpose_body<false>(planes, ws);
  } else {
    int tid = (blockIdx.x - 240) * 256 + threadIdx.x;
    if (bf) prep_body<true >(W1, b1, W2, b2, ws, tid);
    else    prep_body<false>(W1, b1, W2, b2, ws, tid);
  }
}

struct TapInfo {
  float w00, w10, w01, w11;
  int o00, o10, o01, o11;   // texel indices (y*64+x)
};
__device__ __forceinline__ TapInfo tap_setup(float u, float v) {
  TapInfo t;
  float fx = u * 32.0f + 31.5f;
  float fy = v * 32.0f + 31.5f;
  float flx = floorf(fx), fly = floorf(fy);
  int x0 = (int)flx, y0 = (int)fly;
  float wx = fx - flx, wy = fy - fly;
  int x1 = x0 + 1, y1 = y0 + 1;
  bool vx0 = (x0 >= 0) && (x0 < 64);
  bool vx1 = (x1 >= 0) && (x1 < 64);
  bool vy0 = (y0 >= 0) && (y0 < 64);
  bool vy1 = (y1 >= 0) && (y1 < 64);
  int cx0 = min(max(x0, 0), 63), cx1 = min(max(x1, 0), 63);
  int cy0 = min(max(y0, 0), 63), cy1 = min(max(y1, 0), 63);
  t.w00 = (1.0f - wx) * (1.0f - wy) * ((vx0 && vy0) ? 1.0f : 0.0f);
  t.w10 = wx * (1.0f - wy)          * ((vx1 && vy0) ? 1.0f : 0.0f);
  t.w01 = (1.0f - wx) * wy          * ((vx0 && vy1) ? 1.0f : 0.0f);
  t.w11 = wx * wy                   * ((vx1 && vy1) ? 1.0f : 0.0f);
  t.o00 = cy0 * 64 + cx0; t.o10 = cy0 * 64 + cx1;
  t.o01 = cy1 * 64 + cx0; t.o11 = cy1 * 64 + cx1;
  return t;
}

// Block = 1 ray (256 threads). Bilinear folded into MFMA: 4 raw-texel corner
// chains per plane; fold AFTER MFMA in C/D layout. CRITICAL (R14 bug): taps are
// computed in A-layout (row m = lane15) but accumulators live in C/D layout
// (row m = quad*4+reg) — fold weights must be SHUFFLED into C/D layout.
template <bool BF16>
__device__ __forceinline__ void fused_body(const void* __restrict__ ro,
                                           const void* __restrict__ rd,
                                           const float* __restrict__ ws,
                                           void* __restrict__ out,
                                           unsigned short* __restrict__ w1s,
                                           float (*__restrict__ rec)[7],
                                           float* __restrict__ w2s,
                                           float* __restrict__ xfer,
                                           float (*__restrict__ red)[8]) {
  const unsigned short* ptb = (const unsigned short*)((const char*)ws + WSB_PT);
  const float* w2f = (const float*)((const char*)ws + WSB_W2);
  const float* b1f = (const float*)((const char*)ws + WSB_B1);
  const float* b2f = (const float*)((const char*)ws + WSB_B2);

  int tid = threadIdx.x;
  int wave = tid >> 6;
  int lane = tid & 63;
  int lane15 = lane & 15;
  int quad = lane >> 4;
  int ray = blockIdx.x;

  // stage compact W1 (1920 uint4) + W2 into LDS
  {
    const uint4* src = (const uint4*)((const char*)ws + WSB_W1S);
    uint4* dst = (uint4*)w1s;
    #pragma unroll
    for (int t = 0; t < 8; t++) {
      int idx = tid + 256 * t;
      if (idx < 1920) dst[idx] = src[idx];
    }
  }
  if (tid < 256) w2s[tid] = w2f[tid];

  // ray data (uniform across block)
  float ox = ldin<BF16>(ro, (size_t)ray*3+0), oy = ldin<BF16>(ro, (size_t)ray*3+1), oz = ldin<BF16>(ro, (size_t)ray*3+2);
  float dx = ldin<BF16>(rd, (size_t)ray*3+0), dy = ldin<BF16>(rd, (size_t)ray*3+1), dz = ldin<BF16>(rd, (size_t)ray*3+2);
  float o3[3] = {ox, oy, oz}, d3[3] = {dx, dy, dz};
  float tmin = -1e30f, tmax = 1e30f;
  #pragma unroll
  for (int k = 0; k < 3; k++) {
    float sd = (fabsf(d3[k]) < 1e-9f) ? 1e-9f : d3[k];
    float ta = (-0.6f - o3[k]) / sd;
    float tb = ( 0.6f - o3[k]) / sd;
    tmin = fmaxf(tmin, fminf(ta, tb));
    tmax = fminf(tmax, fmaxf(ta, tb));
  }
  float tn = fmaxf(tmin, 0.0f);
  float span = fmaxf(tmax - tn, 0.0f);
  float delta = span * (1.0f / (float)S_PER);
  float b1x[4];
  #pragma unroll
  for (int nb = 0; nb < 4; nb++) b1x[nb] = b1f[nb * 16 + lane15];

  __syncthreads();

  #pragma unroll 1
  for (int it = 0; it < 6; it++) {
    int sbase = it * 16 + wave * 4;

    // ---- feature stage: lane feeds A-row m = lane15 (sample sF, decode d)
    int sF = sbase + (lane15 >> 2);
    int d  = lane15 & 3;
    float depF = tn + span * (((float)sF + 0.5f) * (1.0f / (float)S_PER));
    float px = ox + depF * dx, py = oy + depF * dy, pz = oz + depF * dz;
    if (d == 1) px += 0.01f;
    if (d == 2) py += 0.01f;
    if (d == 3) pz += 0.01f;
    if (d > 0) {
      px = fminf(fmaxf(px, -0.6f), 0.6f);
      py = fminf(fmaxf(py, -0.6f), 0.6f);
      pz = fminf(fmaxf(pz, -0.6f), 0.6f);
    }
    const float inv = 1.0f / 0.6f;
    float ux = px * inv, uy = py * inv, uz = pz * inv;

    f32x4 tot[4];
    #pragma unroll
    for (int nb = 0; nb < 4; nb++) tot[nb] = (f32x4){0.f, 0.f, 0.f, 0.f};

    #pragma unroll 1
    for (int p = 0; p < 3; p++) {
      float u = (p == 2) ? uy : ux;
      float v = (p == 0) ? uy : uz;
      TapInfo tp = tap_setup(u, v);
      const unsigned short* c00p = ptb + (size_t)p * 327680 + tp.o00 * 80 + 8 * quad;
      const unsigned short* c10p = ptb + (size_t)p * 327680 + tp.o10 * 80 + 8 * quad;
      const unsigned short* c01p = ptb + (size_t)p * 327680 + tp.o01 * 80 + 8 * quad;
      const unsigned short* c11p = ptb + (size_t)p * 327680 + tp.o11 * 80 + 8 * quad;
      const unsigned short* w1p = w1s + p * 5120;

      // 4 corner accumulator chains for THIS plane (raw bf16 texels as A)
      f32x4 a0[4], a1[4], a2[4], a3[4];
      #pragma unroll
      for (int nb = 0; nb < 4; nb++) {
        a0[nb] = (f32x4){0.f, 0.f, 0.f, 0.f};
        a1[nb] = (f32x4){0.f, 0.f, 0.f, 0.f};
        a2[nb] = (f32x4){0.f, 0.f, 0.f, 0.f};
        a3[nb] = (f32x4){0.f, 0.f, 0.f, 0.f};
      }

      #pragma unroll
      for (int ccl = 0; ccl < 3; ccl++) {
        uint4 q00 = {0, 0, 0, 0}, q10 = {0, 0, 0, 0}, q01 = {0, 0, 0, 0}, q11 = {0, 0, 0, 0};
        if (ccl < 2 || quad < 2) {   // live lanes (ccl2 quads 2,3 are pad-K)
          q00 = *(const uint4*)(c00p + 32 * ccl);
          q10 = *(const uint4*)(c10p + 32 * ccl);
          q01 = *(const uint4*)(c01p + 32 * ccl);
          q11 = *(const uint4*)(c11p + 32 * ccl);
        }
        short8 f00, f10, f01, f11;
        __builtin_memcpy(&f00, &q00, 16);
        __builtin_memcpy(&f10, &q10, 16);
        __builtin_memcpy(&f01, &q01, 16);
        __builtin_memcpy(&f11, &q11, 16);
        #pragma unroll
        for (int nb = 0; nb < 4; nb++) {
          int boff = (ccl < 2) ? (ccl * 2048 + (nb * 64 + lane) * 8)
                               : (4096 + (nb * 32 + (lane & 31)) * 8);
          short8 bfr = *(const short8*)(w1p + boff);
          a0[nb] = __builtin_amdgcn_mfma_f32_16x16x32_bf16(f00, bfr, a0[nb], 0, 0, 0);
          a1[nb] = __builtin_amdgcn_mfma_f32_16x16x32_bf16(f10, bfr, a1[nb], 0, 0, 0);
          a2[nb] = __builtin_amdgcn_mfma_f32_16x16x32_bf16(f01, bfr, a2[nb], 0, 0, 0);
          a3[nb] = __builtin_amdgcn_mfma_f32_16x16x32_bf16(f11, bfr, a3[nb], 0, 0, 0);
        }
      }

      // fold weights shuffled A-layout -> C/D layout: acc element reg is row
      // m = quad*4+reg; its tap lives in lanes with lane15 == m (same quad: 
      // src = quad*16 + quad*4 + reg).
      f32x4 wv00, wv10, wv01, wv11;
      #pragma unroll
      for (int reg = 0; reg < 4; reg++) {
        int src = (lane & 48) + 4 * quad + reg;
        wv00[reg] = __shfl(tp.w00, src, 64);
        wv10[reg] = __shfl(tp.w10, src, 64);
        wv01[reg] = __shfl(tp.w01, src, 64);
        wv11[reg] = __shfl(tp.w11, src, 64);
      }
      #pragma unroll
      for (int nb = 0; nb < 4; nb++) {
        f32x4 s = tot[nb];
        s = __builtin_elementwise_fma(a0[nb], wv00, s);
        s = __builtin_elementwise_fma(a1[nb], wv10, s);
        s = __builtin_elementwise_fma(a2[nb], wv01, s);
        s = __builtin_elementwise_fma(a3[nb], wv11, s);
        tot[nb] = s;
      }
    }

    // ---- layer 2: lane holds h[m=quad*4+reg][n=nb*16+lane15]; d == reg.
    float vals[7];
    #pragma unroll
    for (int k = 0; k < 7; k++) vals[k] = 0.0f;
    #pragma unroll
    for (int nb = 0; nb < 4; nb++) {
      float4 w2r = *(const float4*)(w2s + (nb * 16 + lane15) * 4);
      float hr0 = fmaxf(tot[nb][0] + b1x[nb], 0.0f);
      vals[0] = fmaf(hr0, w2r.x, vals[0]);
      vals[4] = fmaf(hr0, w2r.y, vals[4]);
      vals[5] = fmaf(hr0, w2r.z, vals[5]);
      vals[6] = fmaf(hr0, w2r.w, vals[6]);
      float hr1 = fmaxf(tot[nb][1] + b1x[nb], 0.0f);
      float hr2 = fmaxf(tot[nb][2] + b1x[nb], 0.0f);
      float hr3 = fmaxf(tot[nb][3] + b1x[nb], 0.0f);
      vals[1] = fmaf(hr1, w2r.x, vals[1]);
      vals[2] = fmaf(hr2, w2r.x, vals[2]);
      vals[3] = fmaf(hr3, w2r.x, vals[3]);
    }
    #pragma unroll
    for (int mask = 1; mask < 16; mask <<= 1) {
      #pragma unroll
      for (int k = 0; k < 7; k++) vals[k] += __shfl_xor(vals[k], mask, 64);
    }

    // ---- park raw sums; nonlinear work deferred to composite phase
    if (lane15 == 0) {
      int sE = sbase + quad;
      #pragma unroll
      for (int k = 0; k < 7; k++) rec[sE][k] = vals[k];
    }
  }

  __syncthreads();

  // ---- composite: per-sample epilogue (96 threads) + shfl scan + shfl reduce
  float b2_0 = b2f[0], b2_1 = b2f[1], b2_2 = b2f[2], b2_3 = b2f[3];
  float a = 0.f, l = 0.f, pcr = 0.f, pcg = 0.f, pcb = 0.f, pnx = 0.f, pny = 0.f, pnz = 0.f, pdt = 0.f;
  if (tid < S_PER) {
    float v0 = rec[tid][0], v1 = rec[tid][1], v2 = rec[tid][2], v3 = rec[tid][3];
    float v4 = rec[tid][4], v5 = rec[tid][5], v6 = rec[tid][6];
    float sdf0 = v0 + b2_0;
    float g0 = (v1 - v0) * 100.0f;
    float g1 = (v2 - v0) * 100.0f;
    float g2 = (v3 - v0) * 100.0f;
    size_t gid = (size_t)ray * S_PER + tid;
    stout<BF16>(out, (size_t)32768 + gid * 3 + 0, g0);
    stout<BF16>(out, (size_t)32768 + gid * 3 + 1, g1);
    stout<BF16>(out, (size_t)32768 + gid * 3 + 2, g2);
    pcr = 1.0f / (1.0f + expf(-(v4 + b2_1))) * 1.002f - 0.001f;
    pcg = 1.0f / (1.0f + expf(-(v5 + b2_2))) * 1.002f - 0.001f;
    pcb = 1.0f / (1.0f + expf(-(v6 + b2_3))) * 1.002f - 0.001f;
    pdt = tn + span * (((float)tid + 0.5f) * (1.0f / (float)S_PER));
    float ex = ox + pdt * dx, ey = oy + pdt * dy, ez = oz + pdt * dz;
    float pn = sqrtf(ex * ex + ey * ey + ez * ez);
    float shifted = sdf0 + pn - 0.5f;
    float xarg = -shifted * 80.0f;
    float sigma = (xarg > 20.0f) ? xarg : log1pf(expf(xarg));
    a = 1.0f - expf(-sigma * delta);
    float gl = sqrtf(g0 * g0 + g1 * g1 + g2 * g2) + 1e-8f;
    float igl = 1.0f / gl;
    pnx = g0 * igl; pny = g1 * igl; pnz = g2 * igl;
    l = logf(1.0f - a + 1e-10f);
  }

  // inclusive prefix over 96 log-terms: wave-scan + 1-float cross-wave fixup
  float lv = l;   // zero for tid >= 96
  #pragma unroll
  for (int off = 1; off < 64; off <<= 1) {
    float up = __shfl_up(lv, off, 64);
    if (lane >= off) lv += up;
  }
  if (tid == 63) xfer[0] = lv;   // total of samples 0..63
  __syncthreads();
  if (tid >= 64 && tid < S_PER) lv += xfer[0];

  float T = expf(lv - l);        // exclusive prefix -> transmittance
  float w = (tid < S_PER) ? a * T : 0.0f;
  float q[8];
  q[0] = w;
  q[1] = w * pcr; q[2] = w * pcg; q[3] = w * pcb;
  q[4] = w * pnx; q[5] = w * pny; q[6] = w * pnz;
  q[7] = w * pdt;
  #pragma unroll
  for (int off = 1; off < 64; off <<= 1) {
    #pragma unroll
    for (int k = 0; k < 8; k++) q[k] += __shfl_xor(q[k], off, 64);
  }
  if (lane == 0) {
    #pragma unroll
    for (int k = 0; k < 8; k++) red[wave][k] = q[k];
  }
  __syncthreads();
  if (tid == 0) {
    float R[8];
    #pragma unroll
    for (int k = 0; k < 8; k++) R[k] = red[0][k] + red[1][k] + red[2][k] + red[3][k];
    float wsum = R[0];
    float nl = sqrtf(R[4] * R[4] + R[5] * R[5] + R[6] * R[6]) + 1e-8f;
    float inl = 1.0f / nl;
    float nrm3[3] = {R[4], R[5], R[6]};
    float rgb3[3] = {R[1], R[2], R[3]};
    #pragma unroll
    for (int c = 0; c < 3; c++) {
      float n = (nrm3[c] * inl + 1.0f) * 0.5f * wsum;
      stout<BF16>(out, (size_t)(c * 4096 + ray), rgb3[c] + 1.0f - wsum);
      stout<BF16>(out, (size_t)(20480 + c * 4096 + ray), n);
    }
    stout<BF16>(out, (size_t)(12288 + ray), R[7]);
    stout<BF16>(out, (size_t)(16384 + ray), wsum);
  }
}

__global__ __launch_bounds__(256) void fused_kernel(
    const void* __restrict__ ro,
    const void* __restrict__ rd,
    const float* __restrict__ ws,
    void* __restrict__ out) {
  __shared__ __align__(16) unsigned short w1s[15360];  // 30 KB compact
  __shared__ float rec[S_PER][7];
  __shared__ float w2s[256];
  __shared__ float xfer[1];
  __shared__ float red[4][8];

  if (detect_bf16(rd)) fused_body<true >(ro, rd, ws, out, w1s, rec, w2s, xfer, red);
  else                 fused_body<false>(ro, rd, ws, out, w1s, rec, w2s, xfer, red);
}

extern "C" void kernel_launch(void* const* d_in, const int* in_sizes, int n_in,
                              void* d_out, int out_size, void* d_ws, size_t ws_size,
                              hipStream_t stream) {
  const void* planes = d_in[0];
  const void* ro     = d_in[1];
  const void* rd     = d_in[2];
  const void* W1     = d_in[3];
  const void* b1     = d_in[4];
  const void* W2     = d_in[5];
  const void* b2     = d_in[6];
  float* ws = (float*)d_ws;

  setup_kernel<<<304, 256, 0, stream>>>(planes, W1, b1, W2, b2, rd, ws);
  fused_kernel<<<NUM_RAYS, 256, 0, stream>>>(ro, rd, ws, d_out);
}

// Round 17
// 269.275 us; speedup vs baseline: 1.2961x; 1.2961x over previous
//
#include <hip/hip_runtime.h>
#include <hip/hip_bf16.h>

#define NUM_RAYS 4096
#define S_PER 96
#define NPTS (NUM_RAYS * S_PER)
#define CCH 80
#define HID 64

// ws layout (byte offsets)
#define WSB_W2     256       // 256 f32 (64x4)
#define WSB_B1     1536      // 64 f32
#define WSB_B2     1856      // 4 f32
#define WSB_W1S    4096      // 15360 bf16 shorts, compact MFMA B-frag order (30720 B)
#define WSB_PT     40960     // 983040 bf16: planesT [p][y*64+x][80]  (1.97 MB)

// w1s compact layout (shorts): plane p base = p*5120;
//  ccl 0,1: + ccl*2048 + (nb*64+lane)*8 + j        (k = 8*quad+j, ch = ccl*32+k)
//  ccl 2:   + 4096     + (nb*32+(lane&31))*8 + j   (quads 0,1 only; ch = 64+8*quad+j)

// d_out layout (elements of output dtype):
// [0) comp_rgb 3*4096 | [12288) depth 4096 | [16384) opacity 4096
// [20480) comp_normal 3*4096 | [32768) sdf_grad 393216*3

typedef __attribute__((ext_vector_type(8))) short short8;
typedef __attribute__((ext_vector_type(4))) float f32x4;
typedef __attribute__((ext_vector_type(2))) float f32x2;

__device__ __forceinline__ float bf2f(__hip_bfloat16 v) { return __bfloat162float(v); }

__device__ __forceinline__ short f2bs(float f) {
  __hip_bfloat16 h = __float2bfloat16(f);
  short s; __builtin_memcpy(&s, &h, 2); return s;
}

template <bool BF16>
__device__ __forceinline__ float ldin(const void* p, size_t i) {
  if (BF16) return bf2f(((const __hip_bfloat16*)p)[i]);
  else      return ((const float*)p)[i];
}
template <bool BF16>
__device__ __forceinline__ void stout(void* p, size_t i, float v) {
  if (BF16) ((__hip_bfloat16*)p)[i] = __float2bfloat16(v);
  else      ((float*)p)[i] = v;
}

// unpack bf16x2 dword -> f32x2. hi half used UNMASKED (contamination <= 2^-8
// relative ~ bf16 rounding; verified absmax 0.375 vs threshold 1.32 in R11/R12).
__device__ __forceinline__ f32x2 unpk2(unsigned u) {
  f32x2 r;
  r.x = __uint_as_float(u << 16);
  r.y = __uint_as_float(u);
  return r;
}

// pack two f32 -> packed bf16x2 (lo in low16, hi in high16)
__device__ __forceinline__ unsigned pack_bf16(float lo, float hi) {
#if __has_builtin(__builtin_amdgcn_cvt_pk_bf16_f32)
  typedef __attribute__((ext_vector_type(2))) __bf16 b2t;
  b2t r = __builtin_amdgcn_cvt_pk_bf16_f32(lo, hi);
  unsigned u; __builtin_memcpy(&u, &r, 4); return u;
#else
  unsigned ul = __float_as_uint(lo) + 0x8000u;   // round-half-up
  unsigned uh = __float_as_uint(hi) + 0x8000u;
  return __builtin_amdgcn_perm(uh, ul, 0x07060302);
#endif
}

// Per-wave dtype self-detection: bf16 ray-dir norms ~1; f32-misread is garbage.
__device__ __forceinline__ bool detect_bf16(const void* rdv) {
  int lane = threadIdx.x & 63;
  const __hip_bfloat16* p = (const __hip_bfloat16*)rdv;
  float x = bf2f(p[lane * 3 + 0]);
  float y = bf2f(p[lane * 3 + 1]);
  float z = bf2f(p[lane * 3 + 2]);
  float n2 = x * x + y * y + z * z;
  bool ok = (n2 > 0.95f) && (n2 < 1.05f);
  return __ballot(ok) == ~0ull;
}

template <bool BF16>
__device__ __forceinline__ void prep_body(const void* __restrict__ W1,
                                          const void* __restrict__ b1,
                                          const void* __restrict__ W2,
                                          const void* __restrict__ b2,
                                          float* __restrict__ ws, int tid) {
  unsigned short* w1sw = (unsigned short*)((char*)ws + WSB_W1S);
  if (tid < 15360) {
    int p = tid / 5120;
    int r = tid - p * 5120;
    int ch, n;
    if (r < 4096) {
      int ccl  = r >> 11;
      int r2   = r & 2047;
      int j    = r2 & 7;
      int lane = (r2 >> 3) & 63;
      int nb   = r2 >> 9;
      ch = ccl * 32 + 8 * (lane >> 4) + j;
      n  = nb * 16 + (lane & 15);
    } else {
      int r2   = r - 4096;
      int j    = r2 & 7;
      int l31  = (r2 >> 3) & 31;
      int nb   = r2 >> 8;
      ch = 64 + 8 * (l31 >> 4) + j;
      n  = nb * 16 + (l31 & 15);
    }
    w1sw[tid] = (unsigned short)f2bs(ldin<BF16>(W1, (size_t)(p * 80 + ch) * 64 + n));
  }
  float* w2f = (float*)((char*)ws + WSB_W2);
  float* b1f = (float*)((char*)ws + WSB_B1);
  float* b2f = (float*)((char*)ws + WSB_B2);
  if (tid < 256) w2f[tid] = ldin<BF16>(W2, tid);
  if (tid < 64)  b1f[tid] = ldin<BF16>(b1, tid);
  if (tid < 4)   b2f[tid] = ldin<BF16>(b2, tid);
}

// planes[p][c][y][x] -> planesT[p][y*64+x][80] (bf16, channel-last).
template <bool BF16>
__device__ __forceinline__ void transpose_body(const void* __restrict__ planes,
                                               float* __restrict__ ws) {
  int b  = blockIdx.x;
  int tt = b & 15;
  int ct = (b >> 4) % 5;
  int p  = b / 80;
  int tex = tt * 256 + threadIdx.x;
  unsigned u[8];
  #pragma unroll
  for (int i = 0; i < 8; i++) {
    int c0 = ct * 16 + 2 * i;
    float v0 = ldin<BF16>(planes, ((size_t)(p * 80 + c0) * 4096) + tex);
    float v1 = ldin<BF16>(planes, ((size_t)(p * 80 + c0 + 1) * 4096) + tex);
    unsigned s0 = (unsigned short)f2bs(v0);
    unsigned s1 = (unsigned short)f2bs(v1);
    u[i] = s0 | (s1 << 16);
  }
  unsigned short* ptb = (unsigned short*)((char*)ws + WSB_PT);
  uint4* dst = (uint4*)(ptb + ((size_t)(p * 4096 + tex) * 80 + ct * 16));
  dst[0] = make_uint4(u[0], u[1], u[2], u[3]);
  dst[1] = make_uint4(u[4], u[5], u[6], u[7]);
}

// blocks 0..239: plane transpose; blocks 240..303: weight prep
__global__ void setup_kernel(const void* __restrict__ planes,
                             const void* __restrict__ W1,
                             const void* __restrict__ b1,
                             const void* __restrict__ W2,
                             const void* __restrict__ b2,
                             const void* __restrict__ rd,
                             float* __restrict__ ws) {
  bool bf = detect_bf16(rd);
  if (blockIdx.x < 240) {
    if (bf) transpose_body<true >(planes, ws);
    else    transpose_body<false>(planes, ws);
  } else {
    int tid = (blockIdx.x - 240) * 256 + threadIdx.x;
    if (bf) prep_body<true >(W1, b1, W2, b2, ws, tid);
    else    prep_body<false>(W1, b1, W2, b2, ws, tid);
  }
}

struct TapInfo {
  float w00, w10, w01, w11;
  int o00, o10, o01, o11;   // texel indices (y*64+x)
};
__device__ __forceinline__ TapInfo tap_setup(float u, float v) {
  TapInfo t;
  float fx = u * 32.0f + 31.5f;
  float fy = v * 32.0f + 31.5f;
  float flx = floorf(fx), fly = floorf(fy);
  int x0 = (int)flx, y0 = (int)fly;
  float wx = fx - flx, wy = fy - fly;
  int x1 = x0 + 1, y1 = y0 + 1;
  bool vx0 = (x0 >= 0) && (x0 < 64);
  bool vx1 = (x1 >= 0) && (x1 < 64);
  bool vy0 = (y0 >= 0) && (y0 < 64);
  bool vy1 = (y1 >= 0) && (y1 < 64);
  int cx0 = min(max(x0, 0), 63), cx1 = min(max(x1, 0), 63);
  int cy0 = min(max(y0, 0), 63), cy1 = min(max(y1, 0), 63);
  t.w00 = (1.0f - wx) * (1.0f - wy) * ((vx0 && vy0) ? 1.0f : 0.0f);
  t.w10 = wx * (1.0f - wy)          * ((vx1 && vy0) ? 1.0f : 0.0f);
  t.w01 = (1.0f - wx) * wy          * ((vx0 && vy1) ? 1.0f : 0.0f);
  t.w11 = wx * wy                   * ((vx1 && vy1) ? 1.0f : 0.0f);
  t.o00 = cy0 * 64 + cx0; t.o10 = cy0 * 64 + cx1;
  t.o01 = cy1 * 64 + cx0; t.o11 = cy1 * 64 + cx1;
  return t;
}

// Block = 1 ray (256 threads) — R12 shape, the measured optimum:
// scalar-bilinear A-frag build (VALU) + single MFMA chain. MFMA-folded
// bilinear (R15) regressed: 4x matrix-pipe work + VGPR 120 occupancy loss
// outweighed the VALU cut. 512-thread/2-ray (R13) also regressed.
template <bool BF16>
__device__ __forceinline__ void fused_body(const void* __restrict__ ro,
                                           const void* __restrict__ rd,
                                           const float* __restrict__ ws,
                                           void* __restrict__ out,
                                           unsigned short* __restrict__ w1s,
                                           float (*__restrict__ rec)[7],
                                           float* __restrict__ w2s,
                                           float* __restrict__ xfer,
                                           float (*__restrict__ red)[8]) {
  const unsigned short* ptb = (const unsigned short*)((const char*)ws + WSB_PT);
  const float* w2f = (const float*)((const char*)ws + WSB_W2);
  const float* b1f = (const float*)((const char*)ws + WSB_B1);
  const float* b2f = (const float*)((const char*)ws + WSB_B2);

  int tid = threadIdx.x;
  int wave = tid >> 6;
  int lane = tid & 63;
  int lane15 = lane & 15;
  int quad = lane >> 4;
  int ray = blockIdx.x;

  // stage compact W1 (1920 uint4) + W2 into LDS
  {
    const uint4* src = (const uint4*)((const char*)ws + WSB_W1S);
    uint4* dst = (uint4*)w1s;
    #pragma unroll
    for (int t = 0; t < 8; t++) {
      int idx = tid + 256 * t;
      if (idx < 1920) dst[idx] = src[idx];
    }
  }
  if (tid < 256) w2s[tid] = w2f[tid];

  // ray data (uniform across block)
  float ox = ldin<BF16>(ro, (size_t)ray*3+0), oy = ldin<BF16>(ro, (size_t)ray*3+1), oz = ldin<BF16>(ro, (size_t)ray*3+2);
  float dx = ldin<BF16>(rd, (size_t)ray*3+0), dy = ldin<BF16>(rd, (size_t)ray*3+1), dz = ldin<BF16>(rd, (size_t)ray*3+2);
  float o3[3] = {ox, oy, oz}, d3[3] = {dx, dy, dz};
  float tmin = -1e30f, tmax = 1e30f;
  #pragma unroll
  for (int k = 0; k < 3; k++) {
    float sd = (fabsf(d3[k]) < 1e-9f) ? 1e-9f : d3[k];
    float ta = (-0.6f - o3[k]) / sd;
    float tb = ( 0.6f - o3[k]) / sd;
    tmin = fmaxf(tmin, fminf(ta, tb));
    tmax = fminf(tmax, fmaxf(ta, tb));
  }
  float tn = fmaxf(tmin, 0.0f);
  float span = fmaxf(tmax - tn, 0.0f);
  float delta = span * (1.0f / (float)S_PER);
  // per-lane b1 (4 VGPRs)
  float b1x[4];
  #pragma unroll
  for (int nb = 0; nb < 4; nb++) b1x[nb] = b1f[nb * 16 + lane15];

  __syncthreads();

  #pragma unroll 1
  for (int it = 0; it < 6; it++) {
    int sbase = it * 16 + wave * 4;

    // ---- feature stage: lane feeds A-row m = lane15 (sample sF, decode d)
    int sF = sbase + (lane15 >> 2);
    int d  = lane15 & 3;
    float depF = tn + span * (((float)sF + 0.5f) * (1.0f / (float)S_PER));
    float px = ox + depF * dx, py = oy + depF * dy, pz = oz + depF * dz;
    if (d == 1) px += 0.01f;
    if (d == 2) py += 0.01f;
    if (d == 3) pz += 0.01f;
    if (d > 0) {
      px = fminf(fmaxf(px, -0.6f), 0.6f);
      py = fminf(fmaxf(py, -0.6f), 0.6f);
      pz = fminf(fmaxf(pz, -0.6f), 0.6f);
    }
    const float inv = 1.0f / 0.6f;
    float ux = px * inv, uy = py * inv, uz = pz * inv;

    f32x4 acc[4];
    #pragma unroll
    for (int nb = 0; nb < 4; nb++) acc[nb] = (f32x4){0.f, 0.f, 0.f, 0.f};

    #pragma unroll 1
    for (int p = 0; p < 3; p++) {
      float u = (p == 2) ? uy : ux;
      float v = (p == 0) ? uy : uz;
      TapInfo t = tap_setup(u, v);
      // hoisted per-plane corner pointers incl. this lane's k-offset (8*quad ch)
      const unsigned short* c00p = ptb + (size_t)p * 327680 + t.o00 * 80 + 8 * quad;
      const unsigned short* c10p = ptb + (size_t)p * 327680 + t.o10 * 80 + 8 * quad;
      const unsigned short* c01p = ptb + (size_t)p * 327680 + t.o01 * 80 + 8 * quad;
      const unsigned short* c11p = ptb + (size_t)p * 327680 + t.o11 * 80 + 8 * quad;
      f32x2 wv00 = {t.w00, t.w00}, wv10 = {t.w10, t.w10};
      f32x2 wv01 = {t.w01, t.w01}, wv11 = {t.w11, t.w11};
      const unsigned short* w1p = w1s + p * 5120;
      #pragma unroll
      for (int ccl = 0; ccl < 3; ccl++) {
        int4 afi = {0, 0, 0, 0};
        if (ccl < 2 || quad < 2) {   // live lanes (ccl2 quads 2,3 are pad-K)
          uint4 q00 = *(const uint4*)(c00p + 32 * ccl);
          uint4 q10 = *(const uint4*)(c10p + 32 * ccl);
          uint4 q01 = *(const uint4*)(c01p + 32 * ccl);
          uint4 q11 = *(const uint4*)(c11p + 32 * ccl);
          unsigned u00[4] = {q00.x, q00.y, q00.z, q00.w};
          unsigned u10[4] = {q10.x, q10.y, q10.z, q10.w};
          unsigned u01[4] = {q01.x, q01.y, q01.z, q01.w};
          unsigned u11[4] = {q11.x, q11.y, q11.z, q11.w};
          int ae[4];
          #pragma unroll
          for (int q = 0; q < 4; q++) {
            f32x2 f = unpk2(u00[q]) * wv00;               // v_pk_mul_f32
            f = __builtin_elementwise_fma(unpk2(u10[q]), wv10, f);
            f = __builtin_elementwise_fma(unpk2(u01[q]), wv01, f);
            f = __builtin_elementwise_fma(unpk2(u11[q]), wv11, f);
            ae[q] = (int)pack_bf16(f.x, f.y);
          }
          afi.x = ae[0]; afi.y = ae[1]; afi.z = ae[2]; afi.w = ae[3];
        }
        short8 afr;
        __builtin_memcpy(&afr, &afi, 16);
        #pragma unroll
        for (int nb = 0; nb < 4; nb++) {
          // compact B-frag: ccl 0,1 full; ccl 2 half (quads 2,3 alias — A is 0)
          int boff = (ccl < 2) ? (ccl * 2048 + (nb * 64 + lane) * 8)
                               : (4096 + (nb * 32 + (lane & 31)) * 8);
          short8 bfr = *(const short8*)(w1p + boff);
          acc[nb] = __builtin_amdgcn_mfma_f32_16x16x32_bf16(afr, bfr, acc[nb], 0, 0, 0);
        }
      }
    }

    // ---- layer 2: lane holds h[m=quad*4+reg][n=nb*16+lane15]; d == reg.
    float vals[7];
    #pragma unroll
    for (int k = 0; k < 7; k++) vals[k] = 0.0f;
    #pragma unroll
    for (int nb = 0; nb < 4; nb++) {
      float4 w2r = *(const float4*)(w2s + (nb * 16 + lane15) * 4);
      float hr0 = fmaxf(acc[nb][0] + b1x[nb], 0.0f);
      vals[0] = fmaf(hr0, w2r.x, vals[0]);
      vals[4] = fmaf(hr0, w2r.y, vals[4]);
      vals[5] = fmaf(hr0, w2r.z, vals[5]);
      vals[6] = fmaf(hr0, w2r.w, vals[6]);
      float hr1 = fmaxf(acc[nb][1] + b1x[nb], 0.0f);
      float hr2 = fmaxf(acc[nb][2] + b1x[nb], 0.0f);
      float hr3 = fmaxf(acc[nb][3] + b1x[nb], 0.0f);
      vals[1] = fmaf(hr1, w2r.x, vals[1]);
      vals[2] = fmaf(hr2, w2r.x, vals[2]);
      vals[3] = fmaf(hr3, w2r.x, vals[3]);
    }
    #pragma unroll
    for (int mask = 1; mask < 16; mask <<= 1) {
      #pragma unroll
      for (int k = 0; k < 7; k++) vals[k] += __shfl_xor(vals[k], mask, 64);
    }

    // ---- park raw sums; nonlinear work deferred to composite phase
    if (lane15 == 0) {
      int sE = sbase + quad;
      #pragma unroll
      for (int k = 0; k < 7; k++) rec[sE][k] = vals[k];
    }
  }

  __syncthreads();

  // ---- composite: per-sample epilogue (96 threads) + shfl scan + shfl reduce
  float b2_0 = b2f[0], b2_1 = b2f[1], b2_2 = b2f[2], b2_3 = b2f[3];
  float a = 0.f, l = 0.f, pcr = 0.f, pcg = 0.f, pcb = 0.f, pnx = 0.f, pny = 0.f, pnz = 0.f, pdt = 0.f;
  if (tid < S_PER) {
    float v0 = rec[tid][0], v1 = rec[tid][1], v2 = rec[tid][2], v3 = rec[tid][3];
    float v4 = rec[tid][4], v5 = rec[tid][5], v6 = rec[tid][6];
    float sdf0 = v0 + b2_0;
    float g0 = (v1 - v0) * 100.0f;
    float g1 = (v2 - v0) * 100.0f;
    float g2 = (v3 - v0) * 100.0f;
    size_t gid = (size_t)ray * S_PER + tid;
    stout<BF16>(out, (size_t)32768 + gid * 3 + 0, g0);
    stout<BF16>(out, (size_t)32768 + gid * 3 + 1, g1);
    stout<BF16>(out, (size_t)32768 + gid * 3 + 2, g2);
    pcr = 1.0f / (1.0f + expf(-(v4 + b2_1))) * 1.002f - 0.001f;
    pcg = 1.0f / (1.0f + expf(-(v5 + b2_2))) * 1.002f - 0.001f;
    pcb = 1.0f / (1.0f + expf(-(v6 + b2_3))) * 1.002f - 0.001f;
    pdt = tn + span * (((float)tid + 0.5f) * (1.0f / (float)S_PER));
    float ex = ox + pdt * dx, ey = oy + pdt * dy, ez = oz + pdt * dz;
    float pn = sqrtf(ex * ex + ey * ey + ez * ez);
    float shifted = sdf0 + pn - 0.5f;
    float xarg = -shifted * 80.0f;
    float sigma = (xarg > 20.0f) ? xarg : log1pf(expf(xarg));
    a = 1.0f - expf(-sigma * delta);
    float gl = sqrtf(g0 * g0 + g1 * g1 + g2 * g2) + 1e-8f;
    float igl = 1.0f / gl;
    pnx = g0 * igl; pny = g1 * igl; pnz = g2 * igl;
    l = logf(1.0f - a + 1e-10f);
  }

  // inclusive prefix over 96 log-terms: wave-scan + 1-float cross-wave fixup
  float lv = l;   // zero for tid >= 96
  #pragma unroll
  for (int off = 1; off < 64; off <<= 1) {
    float up = __shfl_up(lv, off, 64);
    if (lane >= off) lv += up;
  }
  if (tid == 63) xfer[0] = lv;   // total of samples 0..63
  __syncthreads();
  if (tid >= 64 && tid < S_PER) lv += xfer[0];

  float T = expf(lv - l);        // exclusive prefix -> transmittance
  float w = (tid < S_PER) ? a * T : 0.0f;
  float q[8];
  q[0] = w;
  q[1] = w * pcr; q[2] = w * pcg; q[3] = w * pcb;
  q[4] = w * pnx; q[5] = w * pny; q[6] = w * pnz;
  q[7] = w * pdt;
  #pragma unroll
  for (int off = 1; off < 64; off <<= 1) {
    #pragma unroll
    for (int k = 0; k < 8; k++) q[k] += __shfl_xor(q[k], off, 64);
  }
  if (lane == 0) {
    #pragma unroll
    for (int k = 0; k < 8; k++) red[wave][k] = q[k];
  }
  __syncthreads();
  if (tid == 0) {
    float R[8];
    #pragma unroll
    for (int k = 0; k < 8; k++) R[k] = red[0][k] + red[1][k] + red[2][k] + red[3][k];
    float wsum = R[0];
    float nl = sqrtf(R[4] * R[4] + R[5] * R[5] + R[6] * R[6]) + 1e-8f;
    float inl = 1.0f / nl;
    float nrm3[3] = {R[4], R[5], R[6]};
    float rgb3[3] = {R[1], R[2], R[3]};
    #pragma unroll
    for (int c = 0; c < 3; c++) {
      float n = (nrm3[c] * inl + 1.0f) * 0.5f * wsum;
      stout<BF16>(out, (size_t)(c * 4096 + ray), rgb3[c] + 1.0f - wsum);
      stout<BF16>(out, (size_t)(20480 + c * 4096 + ray), n);
    }
    stout<BF16>(out, (size_t)(12288 + ray), R[7]);
    stout<BF16>(out, (size_t)(16384 + ray), wsum);
  }
}

__global__ __launch_bounds__(256) void fused_kernel(
    const void* __restrict__ ro,
    const void* __restrict__ rd,
    const float* __restrict__ ws,
    void* __restrict__ out) {
  __shared__ __align__(16) unsigned short w1s[15360];  // 30 KB compact
  __shared__ float rec[S_PER][7];
  __shared__ float w2s[256];
  __shared__ float xfer[1];
  __shared__ float red[4][8];

  if (detect_bf16(rd)) fused_body<true >(ro, rd, ws, out, w1s, rec, w2s, xfer, red);
  else                 fused_body<false>(ro, rd, ws, out, w1s, rec, w2s, xfer, red);
}

extern "C" void kernel_launch(void* const* d_in, const int* in_sizes, int n_in,
                              void* d_out, int out_size, void* d_ws, size_t ws_size,
                              hipStream_t stream) {
  const void* planes = d_in[0];
  const void* ro     = d_in[1];
  const void* rd     = d_in[2];
  const void* W1     = d_in[3];
  const void* b1     = d_in[4];
  const void* W2     = d_in[5];
  const void* b2     = d_in[6];
  float* ws = (float*)d_ws;

  setup_kernel<<<304, 256, 0, stream>>>(planes, W1, b1, W2, b2, rd, ws);
  fused_kernel<<<NUM_RAYS, 256, 0, stream>>>(ro, rd, ws, d_out);
}